// Round 5
// baseline (658.232 us; speedup 1.0000x reference)
//
#include <hip/hip_runtime.h>
#include <stdint.h>

// KVCacheAttention: B=4, Sq=2048, Scache=6144, Skv=8192, D=1024, scale=1/8.
// Round 5: 256x256 8-wave GEMM with BK=32, TRIPLE-buffered LDS (96 KiB),
// m201-style per-phase interleave {ds_read || gll16-stage(t+2) || barrier ||
// 16 MFMA}, counted vmcnt(4) once per tile (never 0). Coalesced epilogues via
// LDS transpose strips for MODE0/1. Bijective XCD swizzle on all GEMM grids.

#define DM 1024
#define NB 4
#define SQN 2048
#define SCC 6144
#define SKV 8192
#define NSPLIT 2
#define KSP (SKV / NSPLIT)

typedef unsigned short u16;
typedef __attribute__((ext_vector_type(8))) short short8;
typedef __attribute__((ext_vector_type(4))) float f32x4;

__device__ __forceinline__ u16 f2bf(float x) {
  unsigned u = __builtin_bit_cast(unsigned, x);
  u += 0x7fffu + ((u >> 16) & 1u);  // RNE; inputs finite
  return (u16)(u >> 16);
}

__device__ __forceinline__ void gll16(const void* g, void* l) {
  __builtin_amdgcn_global_load_lds(
      (const __attribute__((address_space(1))) void*)g,
      (__attribute__((address_space(3))) void*)l, 16, 0, 0);
}

#define FENCE() asm volatile("" ::: "memory")
#define BARRIER()                      \
  do {                                 \
    FENCE();                           \
    __builtin_amdgcn_s_barrier();      \
    FENCE();                           \
  } while (0)

// ---------------- conversions ----------------
__global__ __launch_bounds__(256) void k_cvt(const float* __restrict__ in,
                                             u16* __restrict__ out, long n4) {
  long i = (long)blockIdx.x * 256 + threadIdx.x;
  long st = (long)gridDim.x * 256;
  for (; i < n4; i += st) {
    float4 v = ((const float4*)in)[i];
    ushort4 u;
    u.x = f2bf(v.x); u.y = f2bf(v.y); u.z = f2bf(v.z); u.w = f2bf(v.w);
    ((ushort4*)out)[i] = u;
  }
}

// cached_key [4][6144][1024] f32 -> K bf16 [4][8192][1024] rows 0..6143
__global__ __launch_bounds__(256) void k_cvt_ck(const float* __restrict__ in,
                                                u16* __restrict__ out) {
  const long n4 = (long)NB * SCC * DM / 4;
  long i = (long)blockIdx.x * 256 + threadIdx.x;
  long st = (long)gridDim.x * 256;
  for (; i < n4; i += st) {
    float4 v = ((const float4*)in)[i];
    ushort4 u;
    u.x = f2bf(v.x); u.y = f2bf(v.y); u.z = f2bf(v.z); u.w = f2bf(v.w);
    long e = i * 4;
    int b = (int)(e / ((long)SCC * DM));
    long rem = e - (long)b * SCC * DM;
    *(ushort4*)(out + (long)b * SKV * DM + rem) = u;
  }
}

// ---------------- V^T builder ----------------
__global__ __launch_bounds__(256) void k_build_vt(const float* __restrict__ cv,
                                                  const u16* __restrict__ vtmp,
                                                  u16* __restrict__ VT) {
  __shared__ u16 t[64][65];
  const int kv0 = blockIdx.x * 64;
  const int d0 = blockIdx.y * 64;
  const int b = blockIdx.z;
  const int c = threadIdx.x & 63;
  const int r4 = threadIdx.x >> 6;
#pragma unroll
  for (int p = 0; p < 16; ++p) {
    int kr = p * 4 + r4;
    int kv = kv0 + kr;
    int d = d0 + c;
    u16 u;
    if (kv < SCC)
      u = f2bf(cv[((long)b * SCC + kv) * DM + d]);
    else
      u = vtmp[((long)b * SQN + (kv - SCC)) * DM + d];
    t[kr][c] = u;
  }
  __syncthreads();
#pragma unroll
  for (int p = 0; p < 16; ++p) {
    int dr = p * 4 + r4;
    VT[((long)b * DM + d0 + dr) * SKV + kv0 + c] = t[c][dr];
  }
}

// ---------------- 256x256xBK32 8-wave triple-buffered NT GEMM ----------------
// 512 thr = 8 waves (2M wr x 4N wc); per-wave out 128x64.
// LDS: bufA[3][256][32] @0 (48 KiB), bufB[3][256][32] @49152. XOR swizzle on
// 16B slots: slot ^= (row&3)^((row>>2)&3), applied via pre-swizzled global
// source (rule 21); ds_read applies the same XOR.
// Tile t consumes buf[t%3]; its 4 phases stage tile t+2 into buf[(t+2)%3]
// (4 gll16 at ph0). vmcnt(4) at ph1 certifies tile t+1 (staged during t-1,
// ~4-phase window). 2 phases/tile: ph0 = {read A(mh0)+B, stage, bar, 16 MFMA,
// bar}; ph1 = {read A(mh1), vmcnt(4), bar, 16 MFMA, bar}.
template <int MODE>
__global__ __launch_bounds__(512, 2) void k_gemm8(
    const u16* __restrict__ A, const u16* __restrict__ B0,
    const u16* __restrict__ B1, const u16* __restrict__ B2,
    void* __restrict__ C0, void* __restrict__ C1, void* __restrict__ C2,
    float* __restrict__ sums, const float* __restrict__ bias0,
    const float* __restrict__ bias1, const float* __restrict__ bias2) {
  extern __shared__ char smem[];
  const int tid = threadIdx.x;
  const int lane = tid & 63;
  const int wv = tid >> 6;   // 0..7
  const int wr = wv >> 2;    // 0..1
  const int wc = wv & 3;     // 0..3

  constexpr int GX = (MODE == 0) ? 12 : (MODE == 1) ? 32 : 4;
  constexpr int GY = (MODE == 0) ? 32 : 8;
  constexpr int NWG = GX * GY * ((MODE == 0) ? 1 : (MODE == 1) ? 4 : 8);
  // bijective XCD swizzle (NWG % 8 == 0)
  int bid = blockIdx.x + GX * (blockIdx.y + GY * blockIdx.z);
  int s = (bid & 7) * (NWG >> 3) + (bid >> 3);
  const int bn = (s % GX) * 256;
  const int bm = ((s / GX) % GY) * 256;
  const int z = s / (GX * GY);

  constexpr int LD = (MODE == 2) ? SKV : DM;
  constexpr int NT = ((MODE == 2) ? KSP : DM) / 32;

  const u16 *Ab, *Bb;
  if constexpr (MODE == 0) {
    Ab = A + (long)bm * LD;
    const int which = bn >> 10;
    const u16* Bsel = which == 0 ? B0 : (which == 1 ? B1 : B2);
    Bb = Bsel + (long)(bn & 1023) * LD;
  } else if constexpr (MODE == 1) {
    Ab = A + ((long)z * SQN + bm) * LD;
    Bb = B0 + ((long)z * SKV + bn) * LD;
  } else {
    const int bb_ = z >> 2, sp = z & 3;  // z = b*NSPLIT...; NSPLIT=2 -> z>>1
    (void)bb_; (void)sp;
  }
  if constexpr (MODE == 2) {
    const int bb_ = z / NSPLIT, sp = z % NSPLIT;
    Ab = A + ((long)bb_ * SQN + bm) * (long)SKV + (long)sp * KSP;
    Bb = B0 + ((long)bb_ * DM + bn) * (long)SKV + (long)sp * KSP;
  }

  // staging: round r in {0,1}: rows r*128 + wv*16 + (lane>>2), src slot
  // pre-swizzled; LDS dest linear (wave-uniform base + lane*16B).
  const int srow = wv * 16 + (lane >> 2);
  const int ssl = ((lane & 3) ^ ((lane >> 2) & 3) ^ ((lane >> 4) & 3)) * 8;
  const u16* gA = Ab + (long)srow * LD + ssl;
  const u16* gB = Bb + (long)srow * LD + ssl;
  u16* lA = (u16*)smem + wv * 512 + lane * 8;            // + buf*8192 + r*4096
  u16* lB = (u16*)(smem + 49152) + wv * 512 + lane * 8;

  // prologue: stage tiles 0 and 1
#pragma unroll
  for (int tt = 0; tt < 2; ++tt) {
    gll16(gA + tt * 32, lA + tt * 8192);
    gll16(gA + tt * 32 + (long)128 * LD, lA + tt * 8192 + 4096);
    gll16(gB + tt * 32, lB + tt * 8192);
    gll16(gB + tt * 32 + (long)128 * LD, lB + tt * 8192 + 4096);
  }
  asm volatile("s_waitcnt vmcnt(4)" ::: "memory");
  BARRIER();

  f32x4 acc[8][4];
#pragma unroll
  for (int m = 0; m < 8; ++m)
#pragma unroll
    for (int n = 0; n < 4; ++n)
#pragma unroll
      for (int j = 0; j < 4; ++j) acc[m][n][j] = 0.0f;

  const int alane = lane & 15;
  const int rslot = (((lane >> 4) ^ (lane & 3) ^ ((lane >> 2) & 3)) * 16);

#define AFR(MH, M)                                                       \
  (*(const short8*)(As + (wr * 128 + (MH)*64 + (M)*16 + alane) * 64 + rslot))
#define BFR(N) \
  (*(const short8*)(Bs + (wc * 64 + (N)*16 + alane) * 64 + rslot))
#define MFMA16(MB)                                                      \
  __builtin_amdgcn_s_setprio(1);                                        \
  _Pragma("unroll") for (int mm = 0; mm < 4; ++mm)                      \
  _Pragma("unroll") for (int nn = 0; nn < 4; ++nn)                      \
      acc[(MB) + mm][nn] = __builtin_amdgcn_mfma_f32_16x16x32_bf16(     \
          aF[mm], bFr[nn], acc[(MB) + mm][nn], 0, 0, 0);                \
  __builtin_amdgcn_s_setprio(0);

  short8 aF[4], bFr[4];
  int cb = 0, pb = 2;
  for (int t = 0; t < NT; ++t) {
    const char* As = smem + cb * 16384;
    const char* Bs = smem + 49152 + cb * 16384;
    u16* lAp = lA + pb * 8192;
    u16* lBp = lB + pb * 8192;
    const long kpre = (long)((t + 2 < NT) ? t + 2 : NT - 1) * 32;

    // ---- phase 0: read A(mh0)+B frags; stage tile t+2; bar; MFMA mh0 ----
#pragma unroll
    for (int m = 0; m < 4; ++m) aF[m] = AFR(0, m);
#pragma unroll
    for (int n = 0; n < 4; ++n) bFr[n] = BFR(n);
    gll16(gA + kpre, lAp);
    gll16(gA + kpre + (long)128 * LD, lAp + 4096);
    gll16(gB + kpre, lBp);
    gll16(gB + kpre + (long)128 * LD, lBp + 4096);
    BARRIER();
    MFMA16(0);
    BARRIER();

    // ---- phase 1: read A(mh1); vmcnt(4) certifies tile t+1; bar; MFMA ----
#pragma unroll
    for (int m = 0; m < 4; ++m) aF[m] = AFR(1, m);
    asm volatile("s_waitcnt vmcnt(4)" ::: "memory");
    BARRIER();
    MFMA16(4);
    BARRIER();

    cb = (cb == 2) ? 0 : cb + 1;
    pb = (pb == 2) ? 0 : pb + 1;
  }
#undef AFR
#undef BFR
#undef MFMA16

  // drain dangling prefetches before reusing LDS for the epilogue strip
  asm volatile("s_waitcnt vmcnt(0)" ::: "memory");
  BARRIER();

  const int rsub = (lane >> 4) * 4;

  if constexpr (MODE == 2) {
    // direct f32 stores (64B segments): acceptable
    float* Cp = (float*)C0 + (long)z * SQN * DM;
#pragma unroll
    for (int n = 0; n < 4; ++n) {
      int col = bn + wc * 64 + n * 16 + alane;
#pragma unroll
      for (int m = 0; m < 8; ++m)
#pragma unroll
        for (int j = 0; j < 4; ++j) {
          int row = bm + wr * 128 + m * 16 + rsub + j;
          Cp[(long)row * DM + col] = acc[m][n][j];
        }
    }
  } else {
    // coalesced store via LDS strip [128][264] u16 (67.6 KB, reuses smem)
    u16* T = (u16*)smem;
    const int rrow = tid >> 2;   // 0..127
    const int rc4 = tid & 3;     // 64-col group
#pragma unroll
    for (int h = 0; h < 2; ++h) {
      if (wr == h) {
        if constexpr (MODE == 1) {
          float* sb = sums + z * SQN;
          const float CE = 0.18033688011112042f;  // log2(e)/8
#pragma unroll
          for (int m = 0; m < 8; ++m)
#pragma unroll
            for (int j = 0; j < 4; ++j) {
              int lrow = m * 16 + rsub + j;
              float part = 0.f;
#pragma unroll
              for (int n = 0; n < 4; ++n) {
                float e = exp2f(acc[m][n][j] * CE);
                part += e;
                T[lrow * 264 + wc * 64 + n * 16 + alane] = f2bf(e);
              }
              part += __shfl_xor(part, 1);
              part += __shfl_xor(part, 2);
              part += __shfl_xor(part, 4);
              part += __shfl_xor(part, 8);
              if (alane == 0) atomicAdd(&sb[bm + h * 128 + lrow], part);
            }
        } else {
          const int which = bn >> 10;
          const float* bp = which == 0 ? bias0 : (which == 1 ? bias1 : bias2);
#pragma unroll
          for (int m = 0; m < 8; ++m)
#pragma unroll
            for (int j = 0; j < 4; ++j) {
              int lrow = m * 16 + rsub + j;
#pragma unroll
              for (int n = 0; n < 4; ++n) {
                int cc = (bn & 1023) + wc * 64 + n * 16 + alane;
                T[lrow * 264 + wc * 64 + n * 16 + alane] =
                    f2bf(acc[m][n][j] + bp[cc]);
              }
            }
        }
      }
      BARRIER();
      {
        int grow = bm + h * 128 + rrow;
        const u16* src = T + rrow * 264 + rc4 * 64;
        if constexpr (MODE == 1) {
          u16* Pp = (u16*)C0 + (long)z * SQN * SKV;
          long gr = (long)grow * SKV + bn + rc4 * 64;
#pragma unroll
          for (int k = 0; k < 8; ++k)
            *(short8*)(Pp + gr + k * 8) = *(const short8*)(src + k * 8);
        } else {
          const int which = bn >> 10;
          int cc = (bn & 1023) + rc4 * 64;
          u16* dst;
          if (which == 1) {
            int b = grow >> 11, ss = grow & 2047;
            dst = (u16*)C1 + ((long)b * SKV + SCC + ss) * DM + cc;
          } else if (which == 0) {
            dst = (u16*)C0 + (long)grow * DM + cc;
          } else {
            dst = (u16*)C2 + (long)grow * DM + cc;
          }
#pragma unroll
          for (int k = 0; k < 8; ++k)
            *(short8*)(dst + k * 8) = *(const short8*)(src + k * 8);
        }
      }
      BARRIER();
    }
  }
}

// ---------------- reduce split-K partials + normalize ----------------
__global__ __launch_bounds__(256) void k_reduce(const float* __restrict__ Op,
                                                const float* __restrict__ sums,
                                                float* __restrict__ out) {
  const long n4 = (long)NB * SQN * DM / 4;
  long i = (long)blockIdx.x * 256 + threadIdx.x;
  if (i >= n4) return;
  long e = i * 4;
  int b = (int)(e / ((long)SQN * DM));
  long rem = e - (long)b * SQN * DM;
  int row = (int)(rem / DM);
  const long z4 = (long)SQN * DM / 4;
  long i0 = (long)(b * NSPLIT) * z4 + (rem >> 2);
  float4 a0 = ((const float4*)Op)[i0];
  float4 a1 = ((const float4*)Op)[i0 + z4];
  float inv = 1.0f / sums[b * SQN + row];
  float4 r;
  r.x = (a0.x + a1.x) * inv;
  r.y = (a0.y + a1.y) * inv;
  r.z = (a0.z + a1.z) * inv;
  r.w = (a0.w + a1.w) * inv;
  ((float4*)out)[i] = r;
}

// ---------------- launch ----------------
extern "C" void kernel_launch(void* const* d_in, const int* in_sizes, int n_in,
                              void* d_out, int out_size, void* d_ws, size_t ws_size,
                              hipStream_t stream) {
  const float* hidden = (const float*)d_in[0];
  const float* ck = (const float*)d_in[1];
  const float* cv = (const float*)d_in[2];
  const float* Wq = (const float*)d_in[3];
  const float* bq = (const float*)d_in[4];
  const float* Wk = (const float*)d_in[5];
  const float* bk = (const float*)d_in[6];
  const float* Wv = (const float*)d_in[7];
  const float* bv = (const float*)d_in[8];
  (void)in_sizes; (void)n_in; (void)out_size; (void)ws_size;

  hipFuncSetAttribute(reinterpret_cast<const void*>(&k_gemm8<0>),
                      hipFuncAttributeMaxDynamicSharedMemorySize, 98304);
  hipFuncSetAttribute(reinterpret_cast<const void*>(&k_gemm8<1>),
                      hipFuncAttributeMaxDynamicSharedMemorySize, 98304);
  hipFuncSetAttribute(reinterpret_cast<const void*>(&k_gemm8<2>),
                      hipFuncAttributeMaxDynamicSharedMemorySize, 98304);

  char* base = (char*)d_ws;
  size_t off = 0;
  auto alloc = [&](size_t bytes) {
    char* p = base + off;
    off = (off + bytes + 255) & ~(size_t)255;
    return p;
  };
  // region0 (dead before PV): Hb, weights, Qb, Kb, Vtmp. Opart aliases it.
  u16* Hb = (u16*)alloc((size_t)NB * SQN * DM * 2);
  u16* Wqb = (u16*)alloc((size_t)DM * DM * 2);
  u16* Wkb = (u16*)alloc((size_t)DM * DM * 2);
  u16* Wvb = (u16*)alloc((size_t)DM * DM * 2);
  u16* Qb = (u16*)alloc((size_t)NB * SQN * DM * 2);
  u16* Kb = (u16*)alloc((size_t)NB * SKV * DM * 2);
  u16* Vtmp = (u16*)alloc((size_t)NB * SQN * DM * 2);
  float* Opart = (float*)base;  // [NB*NSPLIT][2048][1024] f32, aliases region0
  size_t opart_bytes = (size_t)NB * NSPLIT * SQN * DM * 4;
  if (off < opart_bytes) off = (opart_bytes + 255) & ~(size_t)255;
  u16* VT = (u16*)alloc((size_t)NB * DM * SKV * 2);
  u16* P = (u16*)alloc((size_t)NB * SQN * SKV * 2);
  float* sums = (float*)alloc((size_t)NB * SQN * 4);

  // conversions
  k_cvt<<<2048, 256, 0, stream>>>(hidden, Hb, (long)NB * SQN * DM / 4);
  k_cvt<<<512, 256, 0, stream>>>(Wq, Wqb, (long)DM * DM / 4);
  k_cvt<<<512, 256, 0, stream>>>(Wk, Wkb, (long)DM * DM / 4);
  k_cvt<<<512, 256, 0, stream>>>(Wv, Wvb, (long)DM * DM / 4);
  k_cvt_ck<<<4096, 256, 0, stream>>>(ck, Kb);

  // fused QKV projection: M=8192, N=3072, K=1024
  k_gemm8<0><<<dim3(12, 32, 1), 512, 98304, stream>>>(
      Hb, Wqb, Wkb, Wvb, Qb, Kb, Vtmp, nullptr, bq, bk, bv);

  // V^T
  k_build_vt<<<dim3(SKV / 64, DM / 64, NB), 256, 0, stream>>>(cv, Vtmp, VT);

  // S = QK^T with fused exp + row sums (batched over 4)
  hipMemsetAsync(sums, 0, (size_t)NB * SQN * 4, stream);
  k_gemm8<1><<<dim3(SKV / 256, SQN / 256, NB), 512, 98304, stream>>>(
      Qb, Kb, nullptr, nullptr, P, nullptr, nullptr, sums, nullptr, nullptr, nullptr);

  // PV split-K(2): z = b*NSPLIT + split
  k_gemm8<2><<<dim3(DM / 256, SQN / 256, NB * NSPLIT), 512, 98304, stream>>>(
      P, VT, nullptr, nullptr, Opart, nullptr, nullptr, nullptr, nullptr, nullptr, nullptr);

  // reduce partials + normalize
  k_reduce<<<(NB * SQN * DM / 4 + 255) / 256, 256, 0, stream>>>(
      Opart, sums, (float*)d_out);
}

// Round 6
// 568.705 us; speedup vs baseline: 1.1574x; 1.1574x over previous
//
#include <hip/hip_runtime.h>
#include <stdint.h>

// KVCacheAttention: B=4, Sq=2048, Scache=6144, Skv=8192, D=1024, scale=1/8.
// Round 6: round-3 structure (256x256xBK64, 8 waves, double-buffer, 4 phases,
// slot^=row&7 swizzle, 0 bank conflicts) + (A) staging rescheduled 4A@ph0 /
// 4B@ph1 with vmcnt(4) -> min 3-phase latency window (was 1), (B) coalesced
// MODE0/1 epilogues via LDS strip (was 2-byte scatter). No XCD swizzle
// (round-5 evidence: it doubles FETCH here -- L3-resident regime).

#define DM 1024
#define NB 4
#define SQN 2048
#define SCC 6144
#define SKV 8192
#define NSPLIT 2
#define KSP (SKV / NSPLIT)

typedef unsigned short u16;
typedef __attribute__((ext_vector_type(8))) short short8;
typedef __attribute__((ext_vector_type(4))) float f32x4;

__device__ __forceinline__ u16 f2bf(float x) {
  unsigned u = __builtin_bit_cast(unsigned, x);
  u += 0x7fffu + ((u >> 16) & 1u);  // RNE; inputs finite
  return (u16)(u >> 16);
}

__device__ __forceinline__ void gll16(const void* g, void* l) {
  __builtin_amdgcn_global_load_lds(
      (const __attribute__((address_space(1))) void*)g,
      (__attribute__((address_space(3))) void*)l, 16, 0, 0);
}

#define FENCE() asm volatile("" ::: "memory")
#define BARRIER()                      \
  do {                                 \
    FENCE();                           \
    __builtin_amdgcn_s_barrier();      \
    FENCE();                           \
  } while (0)

// ---------------- conversions ----------------
__global__ __launch_bounds__(256) void k_cvt(const float* __restrict__ in,
                                             u16* __restrict__ out, long n4) {
  long i = (long)blockIdx.x * 256 + threadIdx.x;
  long st = (long)gridDim.x * 256;
  for (; i < n4; i += st) {
    float4 v = ((const float4*)in)[i];
    ushort4 u;
    u.x = f2bf(v.x); u.y = f2bf(v.y); u.z = f2bf(v.z); u.w = f2bf(v.w);
    ((ushort4*)out)[i] = u;
  }
}

// cached_key [4][6144][1024] f32 -> K bf16 [4][8192][1024] rows 0..6143
__global__ __launch_bounds__(256) void k_cvt_ck(const float* __restrict__ in,
                                                u16* __restrict__ out) {
  const long n4 = (long)NB * SCC * DM / 4;
  long i = (long)blockIdx.x * 256 + threadIdx.x;
  long st = (long)gridDim.x * 256;
  for (; i < n4; i += st) {
    float4 v = ((const float4*)in)[i];
    ushort4 u;
    u.x = f2bf(v.x); u.y = f2bf(v.y); u.z = f2bf(v.z); u.w = f2bf(v.w);
    long e = i * 4;
    int b = (int)(e / ((long)SCC * DM));
    long rem = e - (long)b * SCC * DM;
    *(ushort4*)(out + (long)b * SKV * DM + rem) = u;
  }
}

// ---------------- V^T builder ----------------
__global__ __launch_bounds__(256) void k_build_vt(const float* __restrict__ cv,
                                                  const u16* __restrict__ vtmp,
                                                  u16* __restrict__ VT) {
  __shared__ u16 t[64][65];
  const int kv0 = blockIdx.x * 64;
  const int d0 = blockIdx.y * 64;
  const int b = blockIdx.z;
  const int c = threadIdx.x & 63;
  const int r4 = threadIdx.x >> 6;
#pragma unroll
  for (int p = 0; p < 16; ++p) {
    int kr = p * 4 + r4;
    int kv = kv0 + kr;
    int d = d0 + c;
    u16 u;
    if (kv < SCC)
      u = f2bf(cv[((long)b * SCC + kv) * DM + d]);
    else
      u = vtmp[((long)b * SQN + (kv - SCC)) * DM + d];
    t[kr][c] = u;
  }
  __syncthreads();
#pragma unroll
  for (int p = 0; p < 16; ++p) {
    int dr = p * 4 + r4;
    VT[((long)b * DM + d0 + dr) * SKV + kv0 + c] = t[c][dr];
  }
}

// ---------------- 256x256xBK64 8-wave NT GEMM ----------------
// 512 thr = 8 waves (2M x 4N); per-wave out 128x64; BK=64 (2 kk-slices).
// LDS 128 KiB: A[2][256][64] @0, B[2][256][64] @65536, XOR-swizzled
// (16B slot ^= row&7) via pre-swizzled global source.
// Staging for tile kt+1: 4 A-loads at ph0 (after vmcnt(4) certifying tile
// kt's 8), 4 B-loads at ph1 -> minimum completion window = 3 phases.
template <int MODE>
__global__ __launch_bounds__(512, 2) void k_gemm8(
    const u16* __restrict__ A, const u16* __restrict__ B0,
    const u16* __restrict__ B1, const u16* __restrict__ B2,
    void* __restrict__ C0, void* __restrict__ C1, void* __restrict__ C2,
    float* __restrict__ sums, const float* __restrict__ bias0,
    const float* __restrict__ bias1, const float* __restrict__ bias2) {
  extern __shared__ char smem[];
  const int tid = threadIdx.x;
  const int lane = tid & 63;
  const int wv = tid >> 6;   // 0..7
  const int wr = wv >> 2;    // 0..1
  const int wc = wv & 3;     // 0..3
  const int bm = blockIdx.y * 256;
  const int bn = blockIdx.x * 256;
  const int z = blockIdx.z;

  constexpr int LD = (MODE == 2) ? SKV : DM;
  constexpr int NT = ((MODE == 2) ? KSP : DM) / 64;

  const u16 *Ab, *Bb;
  if constexpr (MODE == 0) {
    Ab = A + (long)bm * LD;
    const int which = bn >> 10;
    const u16* Bsel = which == 0 ? B0 : (which == 1 ? B1 : B2);
    Bb = Bsel + (long)(bn & 1023) * LD;
  } else if constexpr (MODE == 1) {
    Ab = A + ((long)z * SQN + bm) * LD;
    Bb = B0 + ((long)z * SKV + bn) * LD;
  } else {
    const int bb_ = z / NSPLIT, sp = z % NSPLIT;
    Ab = A + ((long)bb_ * SQN + bm) * (long)SKV + (long)sp * KSP;
    Bb = B0 + ((long)bb_ * DM + bn) * (long)SKV + (long)sp * KSP;
  }

  // staging: wave wv covers rows wv*8+(lane>>3) of each 64-row round;
  // global col pre-swizzled so linear LDS write produces the swizzled tile.
  const int srow = wv * 8 + (lane >> 3);
  const int scol = ((lane & 7) ^ (lane >> 3)) * 8;
  const u16* gA = Ab + (long)srow * LD + scol;
  const u16* gB = Bb + (long)srow * LD + scol;
  u16* lA = (u16*)smem + wv * 512 + lane * 8;            // + buf*16384 + r*4096
  u16* lB = (u16*)(smem + 65536) + wv * 512 + lane * 8;

  // prologue: stage K-tile 0 into buf0 (8 loads outstanding)
#pragma unroll
  for (int r = 0; r < 4; ++r) gll16(gA + (long)r * 64 * LD, lA + r * 4096);
#pragma unroll
  for (int r = 0; r < 4; ++r) gll16(gB + (long)r * 64 * LD, lB + r * 4096);

  f32x4 acc[8][4];
#pragma unroll
  for (int m = 0; m < 8; ++m)
#pragma unroll
    for (int n = 0; n < 4; ++n)
#pragma unroll
      for (int j = 0; j < 4; ++j) acc[m][n][j] = 0.0f;

  const int alane = lane & 15;
  const int sw = lane & 7;   // row&7 == lane&7 for all frag rows
  const int s0 = lane >> 4;  // base 16B slot

#define AFRAG(M, KK)                                                  \
  (*(const short8*)(As + (wr * 128 + (M)*16 + alane) * 128 +          \
                    (((s0 + 4 * (KK)) ^ sw) * 16)))
#define BFRAG(N, KK)                                                  \
  (*(const short8*)(Bs + (wc * 64 + (N)*16 + alane) * 128 +           \
                    (((s0 + 4 * (KK)) ^ sw) * 16)))
#define MFMA16(N0, N1)                                                      \
  __builtin_amdgcn_s_setprio(1);                                            \
  _Pragma("unroll") for (int m = 0; m < 8; ++m) {                           \
    acc[m][N0] = __builtin_amdgcn_mfma_f32_16x16x32_bf16(aF[m], bF[N0],     \
                                                         acc[m][N0], 0, 0, 0); \
    acc[m][N1] = __builtin_amdgcn_mfma_f32_16x16x32_bf16(aF[m], bF[N1],     \
                                                         acc[m][N1], 0, 0, 0); \
  }                                                                         \
  __builtin_amdgcn_s_setprio(0);

  short8 aF[8], bF[4];

  for (int kt = 0; kt < NT; ++kt) {
    const int b = kt & 1;
    const char* As = smem + b * 32768;
    const char* Bs = smem + 65536 + b * 32768;
    const int d = (b ^ 1) * 16384;
    const long knext = (long)((kt + 1 < NT) ? kt + 1 : kt) * 64;
    const u16* gAn = gA + knext;
    const u16* gBn = gB + knext;

    // ---- phase 0: stage A(kt+1) x4; vmcnt(4) certifies tile kt; bar;
    //               read aF+bF (kk0); MFMA n0,n1 ----
    gll16(gAn, lA + d);
    gll16(gAn + (long)64 * LD, lA + d + 4096);
    gll16(gAn + (long)128 * LD, lA + d + 2 * 4096);
    gll16(gAn + (long)192 * LD, lA + d + 3 * 4096);
    asm volatile("s_waitcnt vmcnt(4)" ::: "memory");
    BARRIER();
#pragma unroll
    for (int m = 0; m < 8; ++m) aF[m] = AFRAG(m, 0);
#pragma unroll
    for (int n = 0; n < 4; ++n) bF[n] = BFRAG(n, 0);
    MFMA16(0, 1);
    BARRIER();

    // ---- phase 1: stage B(kt+1) x4; bar; MFMA n2,n3 (kk0) ----
    gll16(gBn, lB + d);
    gll16(gBn + (long)64 * LD, lB + d + 4096);
    gll16(gBn + (long)128 * LD, lB + d + 2 * 4096);
    gll16(gBn + (long)192 * LD, lB + d + 3 * 4096);
    BARRIER();
    MFMA16(2, 3);
    BARRIER();

    // ---- phase 2: read aF+bF (kk1); bar; MFMA n0,n1 (kk1) ----
#pragma unroll
    for (int m = 0; m < 8; ++m) aF[m] = AFRAG(m, 1);
#pragma unroll
    for (int n = 0; n < 4; ++n) bF[n] = BFRAG(n, 1);
    BARRIER();
    MFMA16(0, 1);
    BARRIER();

    // ---- phase 3: bar; MFMA n2,n3 (kk1) ----
    BARRIER();
    MFMA16(2, 3);
    BARRIER();
  }
#undef AFRAG
#undef BFRAG
#undef MFMA16

  // drain dangling (dummy) prefetches before reusing LDS for the strip
  asm volatile("s_waitcnt vmcnt(0)" ::: "memory");
  BARRIER();

  const int rsub = (lane >> 4) * 4;

  if constexpr (MODE == 2) {
    // f32 out, 64B segments per 16 lanes: acceptable as-is
    float* Cp = (float*)C0 + (long)z * SQN * DM;
#pragma unroll
    for (int n = 0; n < 4; ++n) {
      int col = bn + wc * 64 + n * 16 + alane;
#pragma unroll
      for (int m = 0; m < 8; ++m)
#pragma unroll
        for (int j = 0; j < 4; ++j) {
          int row = bm + wr * 128 + m * 16 + rsub + j;
          Cp[(long)row * DM + col] = acc[m][n][j];
        }
    }
  } else {
    // coalesced bf16 store via LDS strip [128][264] u16 (67.6 KB, reuses smem)
    u16* T = (u16*)smem;
    const int rrow = tid >> 2;   // 0..127
    const int rc4 = tid & 3;     // 64-col group
#pragma unroll
    for (int h = 0; h < 2; ++h) {
      if (wr == h) {
        if constexpr (MODE == 1) {
          float* sb = sums + z * SQN;
          const float CE = 0.18033688011112042f;  // log2(e)/8
#pragma unroll
          for (int m = 0; m < 8; ++m)
#pragma unroll
            for (int j = 0; j < 4; ++j) {
              int lrow = m * 16 + rsub + j;
              float part = 0.f;
#pragma unroll
              for (int n = 0; n < 4; ++n) {
                float e = exp2f(acc[m][n][j] * CE);
                part += e;
                T[lrow * 264 + wc * 64 + n * 16 + alane] = f2bf(e);
              }
              part += __shfl_xor(part, 1);
              part += __shfl_xor(part, 2);
              part += __shfl_xor(part, 4);
              part += __shfl_xor(part, 8);
              if (alane == 0) atomicAdd(&sb[bm + h * 128 + lrow], part);
            }
        } else {
          const int which = bn >> 10;
          const float* bp = which == 0 ? bias0 : (which == 1 ? bias1 : bias2);
#pragma unroll
          for (int m = 0; m < 8; ++m)
#pragma unroll
            for (int j = 0; j < 4; ++j) {
              int lrow = m * 16 + rsub + j;
#pragma unroll
              for (int n = 0; n < 4; ++n) {
                int cc = (bn & 1023) + wc * 64 + n * 16 + alane;
                T[lrow * 264 + wc * 64 + n * 16 + alane] =
                    f2bf(acc[m][n][j] + bp[cc]);
              }
            }
        }
      }
      BARRIER();
      {
        int grow = bm + h * 128 + rrow;
        const u16* src = T + rrow * 264 + rc4 * 64;
        if constexpr (MODE == 1) {
          u16* Pp = (u16*)C0 + (long)z * SQN * SKV;
          long gr = (long)grow * SKV + bn + rc4 * 64;
#pragma unroll
          for (int k = 0; k < 8; ++k)
            *(short8*)(Pp + gr + k * 8) = *(const short8*)(src + k * 8);
        } else {
          const int which = bn >> 10;
          int cc = (bn & 1023) + rc4 * 64;
          u16* dst;
          if (which == 1) {
            int b = grow >> 11, ss = grow & 2047;
            dst = (u16*)C1 + ((long)b * SKV + SCC + ss) * DM + cc;
          } else if (which == 0) {
            dst = (u16*)C0 + (long)grow * DM + cc;
          } else {
            dst = (u16*)C2 + (long)grow * DM + cc;
          }
#pragma unroll
          for (int k = 0; k < 8; ++k)
            *(short8*)(dst + k * 8) = *(const short8*)(src + k * 8);
        }
      }
      BARRIER();
    }
  }
}

// ---------------- reduce split-K partials + normalize ----------------
__global__ __launch_bounds__(256) void k_reduce(const float* __restrict__ Op,
                                                const float* __restrict__ sums,
                                                float* __restrict__ out) {
  const long n4 = (long)NB * SQN * DM / 4;
  long i = (long)blockIdx.x * 256 + threadIdx.x;
  if (i >= n4) return;
  long e = i * 4;
  int b = (int)(e / ((long)SQN * DM));
  long rem = e - (long)b * SQN * DM;
  int row = (int)(rem / DM);
  const long z4 = (long)SQN * DM / 4;
  long i0 = (long)(b * NSPLIT) * z4 + (rem >> 2);
  float4 a0 = ((const float4*)Op)[i0];
  float4 a1 = ((const float4*)Op)[i0 + z4];
  float inv = 1.0f / sums[b * SQN + row];
  float4 r;
  r.x = (a0.x + a1.x) * inv;
  r.y = (a0.y + a1.y) * inv;
  r.z = (a0.z + a1.z) * inv;
  r.w = (a0.w + a1.w) * inv;
  ((float4*)out)[i] = r;
}

// ---------------- launch ----------------
extern "C" void kernel_launch(void* const* d_in, const int* in_sizes, int n_in,
                              void* d_out, int out_size, void* d_ws, size_t ws_size,
                              hipStream_t stream) {
  const float* hidden = (const float*)d_in[0];
  const float* ck = (const float*)d_in[1];
  const float* cv = (const float*)d_in[2];
  const float* Wq = (const float*)d_in[3];
  const float* bq = (const float*)d_in[4];
  const float* Wk = (const float*)d_in[5];
  const float* bk = (const float*)d_in[6];
  const float* Wv = (const float*)d_in[7];
  const float* bv = (const float*)d_in[8];
  (void)in_sizes; (void)n_in; (void)out_size; (void)ws_size;

  hipFuncSetAttribute(reinterpret_cast<const void*>(&k_gemm8<0>),
                      hipFuncAttributeMaxDynamicSharedMemorySize, 131072);
  hipFuncSetAttribute(reinterpret_cast<const void*>(&k_gemm8<1>),
                      hipFuncAttributeMaxDynamicSharedMemorySize, 131072);
  hipFuncSetAttribute(reinterpret_cast<const void*>(&k_gemm8<2>),
                      hipFuncAttributeMaxDynamicSharedMemorySize, 131072);

  char* base = (char*)d_ws;
  size_t off = 0;
  auto alloc = [&](size_t bytes) {
    char* p = base + off;
    off = (off + bytes + 255) & ~(size_t)255;
    return p;
  };
  // region0 (dead before PV): Hb, weights, Qb, Kb, Vtmp. Opart aliases it.
  u16* Hb = (u16*)alloc((size_t)NB * SQN * DM * 2);
  u16* Wqb = (u16*)alloc((size_t)DM * DM * 2);
  u16* Wkb = (u16*)alloc((size_t)DM * DM * 2);
  u16* Wvb = (u16*)alloc((size_t)DM * DM * 2);
  u16* Qb = (u16*)alloc((size_t)NB * SQN * DM * 2);
  u16* Kb = (u16*)alloc((size_t)NB * SKV * DM * 2);
  u16* Vtmp = (u16*)alloc((size_t)NB * SQN * DM * 2);
  float* Opart = (float*)base;  // [NB*NSPLIT][2048][1024] f32, aliases region0
  size_t opart_bytes = (size_t)NB * NSPLIT * SQN * DM * 4;
  if (off < opart_bytes) off = (opart_bytes + 255) & ~(size_t)255;
  u16* VT = (u16*)alloc((size_t)NB * DM * SKV * 2);
  u16* P = (u16*)alloc((size_t)NB * SQN * SKV * 2);
  float* sums = (float*)alloc((size_t)NB * SQN * 4);

  // conversions
  k_cvt<<<2048, 256, 0, stream>>>(hidden, Hb, (long)NB * SQN * DM / 4);
  k_cvt<<<512, 256, 0, stream>>>(Wq, Wqb, (long)DM * DM / 4);
  k_cvt<<<512, 256, 0, stream>>>(Wk, Wkb, (long)DM * DM / 4);
  k_cvt<<<512, 256, 0, stream>>>(Wv, Wvb, (long)DM * DM / 4);
  k_cvt_ck<<<4096, 256, 0, stream>>>(ck, Kb);

  // fused QKV projection: M=8192, N=3072, K=1024
  k_gemm8<0><<<dim3(12, 32, 1), 512, 131072, stream>>>(
      Hb, Wqb, Wkb, Wvb, Qb, Kb, Vtmp, nullptr, bq, bk, bv);

  // V^T
  k_build_vt<<<dim3(SKV / 64, DM / 64, NB), 256, 0, stream>>>(cv, Vtmp, VT);

  // S = QK^T with fused exp + row sums (batched over 4)
  hipMemsetAsync(sums, 0, (size_t)NB * SQN * 4, stream);
  k_gemm8<1><<<dim3(SKV / 256, SQN / 256, NB), 512, 131072, stream>>>(
      Qb, Kb, nullptr, nullptr, P, nullptr, nullptr, sums, nullptr, nullptr, nullptr);

  // PV split-K(2): z = b*NSPLIT + split
  k_gemm8<2><<<dim3(DM / 256, SQN / 256, NB * NSPLIT), 512, 131072, stream>>>(
      P, VT, nullptr, nullptr, Opart, nullptr, nullptr, nullptr, nullptr, nullptr, nullptr);

  // reduce partials + normalize
  k_reduce<<<(NB * SQN * DM / 4 + 255) / 256, 256, 0, stream>>>(
      Opart, sums, (float*)d_out);
}

// Round 7
// 475.909 us; speedup vs baseline: 1.3831x; 1.1950x over previous
//
#include <hip/hip_runtime.h>
#include <stdint.h>

// KVCacheAttention: B=4, Sq=2048, Scache=6144, Skv=8192, D=1024, scale=1/8.
// Round 7: round-3 K-loop EXACTLY (best measured: 2 gll16/phase, vmcnt(2)@ph0,
// kk1 frag reads pre-barrier at ph2, 0 bank conflicts) + operand-SWAPPED
// MODE0/MODE1 so the accumulator j-dim (4 consecutive C-rows) is contiguous
// in the output: epilogues store ushort4 (8B) instead of 2B scatter.
// MODE0: A=W-stack[3072][1024], B=H -> Q/K/V with routing + bias (float4).
// MODE1: A=K, B=Q -> S^T tile; store P[q][kv] ushort4 + rowsum atomics.
// MODE2: PV split-K(2) unchanged (A=P, B=VT, f32 64B stores).

#define DM 1024
#define NB 4
#define SQN 2048
#define SCC 6144
#define SKV 8192
#define NSPLIT 2
#define KSP (SKV / NSPLIT)

typedef unsigned short u16;
typedef __attribute__((ext_vector_type(8))) short short8;
typedef __attribute__((ext_vector_type(4))) float f32x4;

__device__ __forceinline__ u16 f2bf(float x) {
  unsigned u = __builtin_bit_cast(unsigned, x);
  u += 0x7fffu + ((u >> 16) & 1u);  // RNE; inputs finite
  return (u16)(u >> 16);
}

__device__ __forceinline__ void gll16(const void* g, void* l) {
  __builtin_amdgcn_global_load_lds(
      (const __attribute__((address_space(1))) void*)g,
      (__attribute__((address_space(3))) void*)l, 16, 0, 0);
}

#define FENCE() asm volatile("" ::: "memory")
#define BARRIER()                      \
  do {                                 \
    FENCE();                           \
    __builtin_amdgcn_s_barrier();      \
    FENCE();                           \
  } while (0)

// ---------------- conversions ----------------
__global__ __launch_bounds__(256) void k_cvt(const float* __restrict__ in,
                                             u16* __restrict__ out, long n4) {
  long i = (long)blockIdx.x * 256 + threadIdx.x;
  long st = (long)gridDim.x * 256;
  for (; i < n4; i += st) {
    float4 v = ((const float4*)in)[i];
    ushort4 u;
    u.x = f2bf(v.x); u.y = f2bf(v.y); u.z = f2bf(v.z); u.w = f2bf(v.w);
    ((ushort4*)out)[i] = u;
  }
}

// cached_key [4][6144][1024] f32 -> K bf16 [4][8192][1024] rows 0..6143
__global__ __launch_bounds__(256) void k_cvt_ck(const float* __restrict__ in,
                                                u16* __restrict__ out) {
  const long n4 = (long)NB * SCC * DM / 4;
  long i = (long)blockIdx.x * 256 + threadIdx.x;
  long st = (long)gridDim.x * 256;
  for (; i < n4; i += st) {
    float4 v = ((const float4*)in)[i];
    ushort4 u;
    u.x = f2bf(v.x); u.y = f2bf(v.y); u.z = f2bf(v.z); u.w = f2bf(v.w);
    long e = i * 4;
    int b = (int)(e / ((long)SCC * DM));
    long rem = e - (long)b * SCC * DM;
    *(ushort4*)(out + (long)b * SKV * DM + rem) = u;
  }
}

// ---------------- V^T builder ----------------
__global__ __launch_bounds__(256) void k_build_vt(const float* __restrict__ cv,
                                                  const u16* __restrict__ vtmp,
                                                  u16* __restrict__ VT) {
  __shared__ u16 t[64][65];
  const int kv0 = blockIdx.x * 64;
  const int d0 = blockIdx.y * 64;
  const int b = blockIdx.z;
  const int c = threadIdx.x & 63;
  const int r4 = threadIdx.x >> 6;
#pragma unroll
  for (int p = 0; p < 16; ++p) {
    int kr = p * 4 + r4;
    int kv = kv0 + kr;
    int d = d0 + c;
    u16 u;
    if (kv < SCC)
      u = f2bf(cv[((long)b * SCC + kv) * DM + d]);
    else
      u = vtmp[((long)b * SQN + (kv - SCC)) * DM + d];
    t[kr][c] = u;
  }
  __syncthreads();
#pragma unroll
  for (int p = 0; p < 16; ++p) {
    int dr = p * 4 + r4;
    VT[((long)b * DM + d0 + dr) * SKV + kv0 + c] = t[c][dr];
  }
}

// ---------------- 256x256xBK64 8-wave NT GEMM (round-3 schedule) ----------------
// 512 thr = 8 waves (2M x 4N); per-wave out 128x64; BK=64 (2 kk-slices).
// LDS 128 KiB: A[2][256][64] @0, B[2][256][64] @65536, XOR-swizzled
// (16B slot ^= row&7) via pre-swizzled global source.
template <int MODE>
__global__ __launch_bounds__(512, 2) void k_gemm8(
    const u16* __restrict__ A, const u16* __restrict__ B0,
    void* __restrict__ C0, void* __restrict__ C1, void* __restrict__ C2,
    float* __restrict__ sums, const float* __restrict__ bias0,
    const float* __restrict__ bias1, const float* __restrict__ bias2) {
  extern __shared__ char smem[];
  const int tid = threadIdx.x;
  const int lane = tid & 63;
  const int wv = tid >> 6;   // 0..7
  const int wr = wv >> 2;    // 0..1
  const int wc = wv & 3;     // 0..3
  const int bm = blockIdx.y * 256;
  const int bn = blockIdx.x * 256;
  const int z = blockIdx.z;

  constexpr int LD = (MODE == 2) ? SKV : DM;
  constexpr int NT = ((MODE == 2) ? KSP : DM) / 64;

  const u16 *Ab, *Bb;
  if constexpr (MODE == 0) {
    Ab = A + (long)bm * LD;          // W-stack rows: out-d 0..3071
    Bb = B0 + (long)bn * LD;         // H tokens
  } else if constexpr (MODE == 1) {
    Ab = A + ((long)z * SKV + bm) * LD;   // K rows: kv
    Bb = B0 + ((long)z * SQN + bn) * LD;  // Q rows: q
  } else {
    const int bb_ = z / NSPLIT, sp = z % NSPLIT;
    Ab = A + ((long)bb_ * SQN + bm) * (long)SKV + (long)sp * KSP;
    Bb = B0 + ((long)bb_ * DM + bn) * (long)SKV + (long)sp * KSP;
  }

  // staging: wave wv covers rows wv*8+(lane>>3) of each 64-row round;
  // global col pre-swizzled so linear LDS write produces the swizzled tile.
  const int srow = wv * 8 + (lane >> 3);
  const int scol = ((lane & 7) ^ (lane >> 3)) * 8;
  const u16* gA = Ab + (long)srow * LD + scol;
  const u16* gB = Bb + (long)srow * LD + scol;
  u16* lA = (u16*)smem + wv * 512 + lane * 8;            // + buf*16384 + r*4096
  u16* lB = (u16*)(smem + 65536) + wv * 512 + lane * 8;

  // prologue: stage K-tile 0 into buf0
#pragma unroll
  for (int r = 0; r < 4; ++r) gll16(gA + (long)r * 64 * LD, lA + r * 4096);
#pragma unroll
  for (int r = 0; r < 4; ++r) gll16(gB + (long)r * 64 * LD, lB + r * 4096);

  f32x4 acc[8][4];
#pragma unroll
  for (int m = 0; m < 8; ++m)
#pragma unroll
    for (int n = 0; n < 4; ++n)
#pragma unroll
      for (int j = 0; j < 4; ++j) acc[m][n][j] = 0.0f;

  const int alane = lane & 15;
  const int sw = lane & 7;   // row&7 == lane&7 for all frag rows
  const int s0 = lane >> 4;  // base 16B slot

#define AFRAG(M, KK)                                                  \
  (*(const short8*)(As + (wr * 128 + (M)*16 + alane) * 128 +          \
                    (((s0 + 4 * (KK)) ^ sw) * 16)))
#define BFRAG(N, KK)                                                  \
  (*(const short8*)(Bs + (wc * 64 + (N)*16 + alane) * 128 +           \
                    (((s0 + 4 * (KK)) ^ sw) * 16)))
#define MFMA16(N0, N1)                                                      \
  __builtin_amdgcn_s_setprio(1);                                            \
  _Pragma("unroll") for (int m = 0; m < 8; ++m) {                           \
    acc[m][N0] = __builtin_amdgcn_mfma_f32_16x16x32_bf16(aF[m], bF[N0],     \
                                                         acc[m][N0], 0, 0, 0); \
    acc[m][N1] = __builtin_amdgcn_mfma_f32_16x16x32_bf16(aF[m], bF[N1],     \
                                                         acc[m][N1], 0, 0, 0); \
  }                                                                         \
  __builtin_amdgcn_s_setprio(0);

  short8 aF[8], bF[4];

  for (int kt = 0; kt < NT; ++kt) {
    const int b = kt & 1;
    const char* As = smem + b * 32768;
    const char* Bs = smem + 65536 + b * 32768;
    const int d = (b ^ 1) * 16384;
    const long knext = (long)((kt + 1 < NT) ? kt + 1 : kt) * 64;
    const u16* gAn = gA + knext;
    const u16* gBn = gB + knext;

    // ---- phase 0: stage A r0,r1; vmcnt(2); bar; read kk0; MFMA n0,n1 ----
    gll16(gAn, lA + d);
    gll16(gAn + (long)64 * LD, lA + d + 4096);
    asm volatile("s_waitcnt vmcnt(2)" ::: "memory");
    BARRIER();
#pragma unroll
    for (int m = 0; m < 8; ++m) aF[m] = AFRAG(m, 0);
#pragma unroll
    for (int n = 0; n < 4; ++n) bF[n] = BFRAG(n, 0);
    MFMA16(0, 1);
    BARRIER();

    // ---- phase 1: stage A r2,r3; bar; MFMA n2,n3 (kk0) ----
    gll16(gAn + (long)128 * LD, lA + d + 2 * 4096);
    gll16(gAn + (long)192 * LD, lA + d + 3 * 4096);
    BARRIER();
    MFMA16(2, 3);
    BARRIER();

    // ---- phase 2: read kk1 (pre-barrier); stage B r0,r1; bar; MFMA ----
#pragma unroll
    for (int m = 0; m < 8; ++m) aF[m] = AFRAG(m, 1);
#pragma unroll
    for (int n = 0; n < 4; ++n) bF[n] = BFRAG(n, 1);
    gll16(gBn, lB + d);
    gll16(gBn + (long)64 * LD, lB + d + 4096);
    BARRIER();
    MFMA16(0, 1);
    BARRIER();

    // ---- phase 3: stage B r2,r3; bar; MFMA n2,n3 (kk1) ----
    gll16(gBn + (long)128 * LD, lB + d + 2 * 4096);
    gll16(gBn + (long)192 * LD, lB + d + 3 * 4096);
    BARRIER();
    MFMA16(2, 3);
    BARRIER();
  }
#undef AFRAG
#undef BFRAG
#undef MFMA16

  // ---------------- epilogue (j-dim contiguous in output) ----------------
  const int rsub = (lane >> 4) * 4;

  if constexpr (MODE == 0) {
    // acc row = out-d, col = token. which = bm>>10 uniform per block.
    const int which = bm >> 10;
    const float* bp = which == 0 ? bias0 : (which == 1 ? bias1 : bias2);
    u16* Cq = (u16*)C0;
    u16* Ck = (u16*)C1;
    u16* Cv = (u16*)C2;
    const int od_base = (bm & 1023) + wr * 128 + rsub;
#pragma unroll
    for (int n = 0; n < 4; ++n) {
      int token = bn + wc * 64 + n * 16 + alane;
      u16* dst;
      if (which == 1) {
        int b = token >> 11, ss = token & 2047;
        dst = Ck + ((long)b * SKV + SCC + ss) * DM;
      } else if (which == 0) {
        dst = Cq + (long)token * DM;
      } else {
        dst = Cv + (long)token * DM;
      }
#pragma unroll
      for (int m = 0; m < 8; ++m) {
        int cc = od_base + m * 16;
        float4 bb = *(const float4*)(bp + cc);
        ushort4 u;
        u.x = f2bf(acc[m][n][0] + bb.x);
        u.y = f2bf(acc[m][n][1] + bb.y);
        u.z = f2bf(acc[m][n][2] + bb.z);
        u.w = f2bf(acc[m][n][3] + bb.w);
        *(ushort4*)(dst + cc) = u;
      }
    }
  } else if constexpr (MODE == 1) {
    // acc row = kv, col = q. store P[q][kv] ushort4; rowsum per q.
    u16* Pp = (u16*)C0 + (long)z * SQN * SKV;
    float* sb = sums + z * SQN;
    const float CE = 0.18033688011112042f;  // log2(e)/8
    const int kv_base = bm + wr * 128 + rsub;
#pragma unroll
    for (int n = 0; n < 4; ++n) {
      int q = bn + wc * 64 + n * 16 + alane;
      u16* prow = Pp + (long)q * SKV;
      float part = 0.f;
#pragma unroll
      for (int m = 0; m < 8; ++m) {
        int kv = kv_base + m * 16;
        float e0 = exp2f(acc[m][n][0] * CE);
        float e1 = exp2f(acc[m][n][1] * CE);
        float e2 = exp2f(acc[m][n][2] * CE);
        float e3 = exp2f(acc[m][n][3] * CE);
        part += (e0 + e1) + (e2 + e3);
        ushort4 u;
        u.x = f2bf(e0); u.y = f2bf(e1); u.z = f2bf(e2); u.w = f2bf(e3);
        *(ushort4*)(prow + kv) = u;
      }
      part += __shfl_xor(part, 16);
      part += __shfl_xor(part, 32);
      if ((lane >> 4) == 0) atomicAdd(&sb[q], part);
    }
  } else {
    // acc row = q, col = d. f32 stores, 64B segments per 16 lanes.
    float* Cp = (float*)C0 + (long)z * SQN * DM;
#pragma unroll
    for (int n = 0; n < 4; ++n) {
      int col = bn + wc * 64 + n * 16 + alane;
#pragma unroll
      for (int m = 0; m < 8; ++m)
#pragma unroll
        for (int j = 0; j < 4; ++j) {
          int row = bm + wr * 128 + m * 16 + rsub + j;
          Cp[(long)row * DM + col] = acc[m][n][j];
        }
    }
  }
}

// ---------------- reduce split-K partials + normalize ----------------
__global__ __launch_bounds__(256) void k_reduce(const float* __restrict__ Op,
                                                const float* __restrict__ sums,
                                                float* __restrict__ out) {
  const long n4 = (long)NB * SQN * DM / 4;
  long i = (long)blockIdx.x * 256 + threadIdx.x;
  if (i >= n4) return;
  long e = i * 4;
  int b = (int)(e / ((long)SQN * DM));
  long rem = e - (long)b * SQN * DM;
  int row = (int)(rem / DM);
  const long z4 = (long)SQN * DM / 4;
  long i0 = (long)(b * NSPLIT) * z4 + (rem >> 2);
  float4 a0 = ((const float4*)Op)[i0];
  float4 a1 = ((const float4*)Op)[i0 + z4];
  float inv = 1.0f / sums[b * SQN + row];
  float4 r;
  r.x = (a0.x + a1.x) * inv;
  r.y = (a0.y + a1.y) * inv;
  r.z = (a0.z + a1.z) * inv;
  r.w = (a0.w + a1.w) * inv;
  ((float4*)out)[i] = r;
}

// ---------------- launch ----------------
extern "C" void kernel_launch(void* const* d_in, const int* in_sizes, int n_in,
                              void* d_out, int out_size, void* d_ws, size_t ws_size,
                              hipStream_t stream) {
  const float* hidden = (const float*)d_in[0];
  const float* ck = (const float*)d_in[1];
  const float* cv = (const float*)d_in[2];
  const float* Wq = (const float*)d_in[3];
  const float* bq = (const float*)d_in[4];
  const float* Wk = (const float*)d_in[5];
  const float* bk = (const float*)d_in[6];
  const float* Wv = (const float*)d_in[7];
  const float* bv = (const float*)d_in[8];
  (void)in_sizes; (void)n_in; (void)out_size; (void)ws_size;

  hipFuncSetAttribute(reinterpret_cast<const void*>(&k_gemm8<0>),
                      hipFuncAttributeMaxDynamicSharedMemorySize, 131072);
  hipFuncSetAttribute(reinterpret_cast<const void*>(&k_gemm8<1>),
                      hipFuncAttributeMaxDynamicSharedMemorySize, 131072);
  hipFuncSetAttribute(reinterpret_cast<const void*>(&k_gemm8<2>),
                      hipFuncAttributeMaxDynamicSharedMemorySize, 131072);

  char* base = (char*)d_ws;
  size_t off = 0;
  auto alloc = [&](size_t bytes) {
    char* p = base + off;
    off = (off + bytes + 255) & ~(size_t)255;
    return p;
  };
  // region0 (dead before PV): Hb, weights, Qb, Kb, Vtmp. Opart aliases it.
  u16* Hb = (u16*)alloc((size_t)NB * SQN * DM * 2);
  u16* Wall = (u16*)alloc((size_t)3 * DM * DM * 2);  // Wq|Wk|Wv stacked
  u16* Qb = (u16*)alloc((size_t)NB * SQN * DM * 2);
  u16* Kb = (u16*)alloc((size_t)NB * SKV * DM * 2);
  u16* Vtmp = (u16*)alloc((size_t)NB * SQN * DM * 2);
  float* Opart = (float*)base;  // [NB*NSPLIT][2048][1024] f32, aliases region0
  size_t opart_bytes = (size_t)NB * NSPLIT * SQN * DM * 4;
  if (off < opart_bytes) off = (opart_bytes + 255) & ~(size_t)255;
  u16* VT = (u16*)alloc((size_t)NB * DM * SKV * 2);
  u16* P = (u16*)alloc((size_t)NB * SQN * SKV * 2);
  float* sums = (float*)alloc((size_t)NB * SQN * 4);

  // conversions
  k_cvt<<<2048, 256, 0, stream>>>(hidden, Hb, (long)NB * SQN * DM / 4);
  k_cvt<<<512, 256, 0, stream>>>(Wq, Wall, (long)DM * DM / 4);
  k_cvt<<<512, 256, 0, stream>>>(Wk, Wall + (size_t)DM * DM, (long)DM * DM / 4);
  k_cvt<<<512, 256, 0, stream>>>(Wv, Wall + (size_t)2 * DM * DM, (long)DM * DM / 4);
  k_cvt_ck<<<4096, 256, 0, stream>>>(ck, Kb);

  // fused QKV projection: A=W-stack [3072][1024], B=H [8192][1024]
  k_gemm8<0><<<dim3(32, 12, 1), 512, 131072, stream>>>(
      Wall, Hb, Qb, Kb, Vtmp, nullptr, bq, bk, bv);

  // V^T
  k_build_vt<<<dim3(SKV / 64, DM / 64, NB), 256, 0, stream>>>(cv, Vtmp, VT);

  // S^T = K.Q^T with fused exp + row sums (batched over 4): A=K, B=Q
  hipMemsetAsync(sums, 0, (size_t)NB * SQN * 4, stream);
  k_gemm8<1><<<dim3(SQN / 256, SKV / 256, NB), 512, 131072, stream>>>(
      Kb, Qb, P, nullptr, nullptr, sums, nullptr, nullptr, nullptr);

  // PV split-K(2): z = b*NSPLIT + split
  k_gemm8<2><<<dim3(DM / 256, SQN / 256, NB * NSPLIT), 512, 131072, stream>>>(
      P, VT, Opart, nullptr, nullptr, nullptr, nullptr, nullptr, nullptr);

  // reduce partials + normalize
  k_reduce<<<(NB * SQN * DM / 4 + 255) / 256, 256, 0, stream>>>(
      Opart, sums, (float*)d_out);
}

// Round 8
// 471.299 us; speedup vs baseline: 1.3966x; 1.0098x over previous
//
#include <hip/hip_runtime.h>
#include <stdint.h>

// KVCacheAttention: B=4, Sq=2048, Scache=6144, Skv=8192, D=1024, scale=1/8.
// Round 8: round-7 K-loop + software-pipelined LDS fragment reads (m201-style):
// quadrant phases (m-half x kk), next phase's frags read via inline-asm
// ds_read_b128 DURING the current MFMA cluster, counted lgkmcnt + sched_barrier
// fences (rule 18). Staging rhythm / vmcnt(2) / barriers IDENTICAL to round 7.
// Epilogues: round-7 operand-swapped coalesced stores.

#define DM 1024
#define NB 4
#define SQN 2048
#define SCC 6144
#define SKV 8192
#define NSPLIT 2
#define KSP (SKV / NSPLIT)

typedef unsigned short u16;
typedef __attribute__((ext_vector_type(8))) short short8;
typedef __attribute__((ext_vector_type(4))) float f32x4;

__device__ __forceinline__ u16 f2bf(float x) {
  unsigned u = __builtin_bit_cast(unsigned, x);
  u += 0x7fffu + ((u >> 16) & 1u);  // RNE; inputs finite
  return (u16)(u >> 16);
}

__device__ __forceinline__ void gll16(const void* g, void* l) {
  __builtin_amdgcn_global_load_lds(
      (const __attribute__((address_space(1))) void*)g,
      (__attribute__((address_space(3))) void*)l, 16, 0, 0);
}

#define FENCE() asm volatile("" ::: "memory")
#define BARRIER()                      \
  do {                                 \
    FENCE();                           \
    __builtin_amdgcn_s_barrier();      \
    FENCE();                           \
  } while (0)

// inline-asm LDS read: backend inserts no auto-waits for asm outputs, so the
// counted LGKM below is the only consumer-side wait (that's the point).
#define DSR(d, a, I) \
  asm volatile("ds_read_b128 %0, %1 offset:" #I : "=v"(d) : "v"(a))

// rule 18: counted wait + full scheduling fence so MFMA can't hoist past it.
#define LGKM(N)                                   \
  do {                                            \
    asm volatile("s_waitcnt lgkmcnt(" #N ")");    \
    __builtin_amdgcn_sched_barrier(0);            \
  } while (0)

#define MFMAQ(AF, BF, MB)                                                   \
  do {                                                                      \
    __builtin_amdgcn_s_setprio(1);                                          \
    _Pragma("unroll") for (int m = 0; m < 4; ++m)                           \
        _Pragma("unroll") for (int n = 0; n < 4; ++n) acc[(MB) + m][n] =    \
        __builtin_amdgcn_mfma_f32_16x16x32_bf16(AF[m], BF[n],               \
                                                acc[(MB) + m][n], 0, 0, 0); \
    __builtin_amdgcn_s_setprio(0);                                          \
    __builtin_amdgcn_sched_barrier(0);                                      \
  } while (0)

// ---------------- conversions ----------------
__global__ __launch_bounds__(256) void k_cvt(const float* __restrict__ in,
                                             u16* __restrict__ out, long n4) {
  long i = (long)blockIdx.x * 256 + threadIdx.x;
  long st = (long)gridDim.x * 256;
  for (; i < n4; i += st) {
    float4 v = ((const float4*)in)[i];
    ushort4 u;
    u.x = f2bf(v.x); u.y = f2bf(v.y); u.z = f2bf(v.z); u.w = f2bf(v.w);
    ((ushort4*)out)[i] = u;
  }
}

// cached_key [4][6144][1024] f32 -> K bf16 [4][8192][1024] rows 0..6143
__global__ __launch_bounds__(256) void k_cvt_ck(const float* __restrict__ in,
                                                u16* __restrict__ out) {
  const long n4 = (long)NB * SCC * DM / 4;
  long i = (long)blockIdx.x * 256 + threadIdx.x;
  long st = (long)gridDim.x * 256;
  for (; i < n4; i += st) {
    float4 v = ((const float4*)in)[i];
    ushort4 u;
    u.x = f2bf(v.x); u.y = f2bf(v.y); u.z = f2bf(v.z); u.w = f2bf(v.w);
    long e = i * 4;
    int b = (int)(e / ((long)SCC * DM));
    long rem = e - (long)b * SCC * DM;
    *(ushort4*)(out + (long)b * SKV * DM + rem) = u;
  }
}

// ---------------- V^T builder ----------------
__global__ __launch_bounds__(256) void k_build_vt(const float* __restrict__ cv,
                                                  const u16* __restrict__ vtmp,
                                                  u16* __restrict__ VT) {
  __shared__ u16 t[64][65];
  const int kv0 = blockIdx.x * 64;
  const int d0 = blockIdx.y * 64;
  const int b = blockIdx.z;
  const int c = threadIdx.x & 63;
  const int r4 = threadIdx.x >> 6;
#pragma unroll
  for (int p = 0; p < 16; ++p) {
    int kr = p * 4 + r4;
    int kv = kv0 + kr;
    int d = d0 + c;
    u16 u;
    if (kv < SCC)
      u = f2bf(cv[((long)b * SCC + kv) * DM + d]);
    else
      u = vtmp[((long)b * SQN + (kv - SCC)) * DM + d];
    t[kr][c] = u;
  }
  __syncthreads();
#pragma unroll
  for (int p = 0; p < 16; ++p) {
    int dr = p * 4 + r4;
    VT[((long)b * DM + d0 + dr) * SKV + kv0 + c] = t[c][dr];
  }
}

// ---------------- 256x256xBK64 8-wave NT GEMM (pipelined frags) ----------------
// 512 thr = 8 waves (2M x 4N); per-wave out 128x64; BK=64 (2 kk-slices).
// LDS 128 KiB: A[2][256][64] @0, B[2][256][64] @65536, XOR-swizzled
// (16B slot ^= row&7) via pre-swizzled global source.
template <int MODE>
__global__ __launch_bounds__(512, 2) void k_gemm8(
    const u16* __restrict__ A, const u16* __restrict__ B0,
    void* __restrict__ C0, void* __restrict__ C1, void* __restrict__ C2,
    float* __restrict__ sums, const float* __restrict__ bias0,
    const float* __restrict__ bias1, const float* __restrict__ bias2) {
  extern __shared__ char smem[];
  const int tid = threadIdx.x;
  const int lane = tid & 63;
  const int wv = tid >> 6;   // 0..7
  const int wr = wv >> 2;    // 0..1
  const int wc = wv & 3;     // 0..3
  const int bm = blockIdx.y * 256;
  const int bn = blockIdx.x * 256;
  const int z = blockIdx.z;

  constexpr int LD = (MODE == 2) ? SKV : DM;
  constexpr int NT = ((MODE == 2) ? KSP : DM) / 64;

  const u16 *Ab_, *Bb_;
  if constexpr (MODE == 0) {
    Ab_ = A + (long)bm * LD;          // W-stack rows: out-d 0..3071
    Bb_ = B0 + (long)bn * LD;         // H tokens
  } else if constexpr (MODE == 1) {
    Ab_ = A + ((long)z * SKV + bm) * LD;   // K rows: kv
    Bb_ = B0 + ((long)z * SQN + bn) * LD;  // Q rows: q
  } else {
    const int bb_ = z / NSPLIT, sp = z % NSPLIT;
    Ab_ = A + ((long)bb_ * SQN + bm) * (long)SKV + (long)sp * KSP;
    Bb_ = B0 + ((long)bb_ * DM + bn) * (long)SKV + (long)sp * KSP;
  }

  // staging: wave wv covers rows wv*8+(lane>>3) of each 64-row round;
  // global col pre-swizzled so linear LDS write produces the swizzled tile.
  const int srow = wv * 8 + (lane >> 3);
  const int scol = ((lane & 7) ^ (lane >> 3)) * 8;
  const u16* gA = Ab_ + (long)srow * LD + scol;
  const u16* gB = Bb_ + (long)srow * LD + scol;
  u16* lA = (u16*)smem + wv * 512 + lane * 8;            // + buf*16384 + r*4096
  u16* lB = (u16*)(smem + 65536) + wv * 512 + lane * 8;

  // prologue: stage K-tile 0 into buf0
#pragma unroll
  for (int r = 0; r < 4; ++r) gll16(gA + (long)r * 64 * LD, lA + r * 4096);
#pragma unroll
  for (int r = 0; r < 4; ++r) gll16(gB + (long)r * 64 * LD, lB + r * 4096);

  f32x4 acc[8][4];
#pragma unroll
  for (int m = 0; m < 8; ++m)
#pragma unroll
    for (int n = 0; n < 4; ++n)
#pragma unroll
      for (int j = 0; j < 4; ++j) acc[m][n][j] = 0.0f;

  const int alane = lane & 15;
  const int sw = lane & 7;   // row&7 == lane&7 for all frag rows
  const int s0 = lane >> 4;  // base 16B slot
  const int slot0 = ((s0 ^ sw) * 16);
  const int slot1 = (((s0 + 4) ^ sw) * 16);
  const int arow_b = (wr * 128 + alane) * 128;
  const int brow_b = (wc * 64 + alane) * 128;

  short8 Aa[4], Abf[4], Bf0[4], Bf1[4];

  for (int kt = 0; kt < NT; ++kt) {
    const int bsel = (kt & 1) * 32768;
    const int d = ((kt & 1) ^ 1) * 16384;
    const long knext = (long)((kt + 1 < NT) ? kt + 1 : kt) * 64;
    const u16* gAn = gA + knext;
    const u16* gBn = gB + knext;
    const int a0 = bsel + arow_b + slot0;          // A kk0
    const int a1 = bsel + arow_b + slot1;          // A kk1
    const int b0 = 65536 + bsel + brow_b + slot0;  // B kk0
    const int b1 = 65536 + bsel + brow_b + slot1;  // B kk1

    // ---- ph0: stage A r0,r1; vmcnt(2) certifies tile kt; bar;
    //           read A(m0,k0)+B(k0)+A(m1,k0); lgkm(4); MFMA (m0,k0) ----
    gll16(gAn, lA + d);
    gll16(gAn + (long)64 * LD, lA + d + 4096);
    asm volatile("s_waitcnt vmcnt(2)" ::: "memory");
    BARRIER();
    DSR(Aa[0], a0, 0); DSR(Aa[1], a0, 2048);
    DSR(Aa[2], a0, 4096); DSR(Aa[3], a0, 6144);
    DSR(Bf0[0], b0, 0); DSR(Bf0[1], b0, 2048);
    DSR(Bf0[2], b0, 4096); DSR(Bf0[3], b0, 6144);
    DSR(Abf[0], a0, 8192); DSR(Abf[1], a0, 10240);
    DSR(Abf[2], a0, 12288); DSR(Abf[3], a0, 14336);
    LGKM(4);
    MFMAQ(Aa, Bf0, 0);
    BARRIER();

    // ---- ph1: read A(m0,k1)+B(k1) (overlap); stage A r2,r3; bar;
    //           lgkm(8) -> A(m1,k0) ready; MFMA (m1,k0) ----
    DSR(Aa[0], a1, 0); DSR(Aa[1], a1, 2048);
    DSR(Aa[2], a1, 4096); DSR(Aa[3], a1, 6144);
    DSR(Bf1[0], b1, 0); DSR(Bf1[1], b1, 2048);
    DSR(Bf1[2], b1, 4096); DSR(Bf1[3], b1, 6144);
    gll16(gAn + (long)128 * LD, lA + d + 2 * 4096);
    gll16(gAn + (long)192 * LD, lA + d + 3 * 4096);
    BARRIER();
    LGKM(8);
    MFMAQ(Abf, Bf0, 4);
    BARRIER();

    // ---- ph2: read A(m1,k1) (overlap); stage B r0,r1; bar;
    //           lgkm(4) -> A(m0,k1)+B(k1) ready; MFMA (m0,k1) ----
    DSR(Abf[0], a1, 8192); DSR(Abf[1], a1, 10240);
    DSR(Abf[2], a1, 12288); DSR(Abf[3], a1, 14336);
    gll16(gBn, lB + d);
    gll16(gBn + (long)64 * LD, lB + d + 4096);
    BARRIER();
    LGKM(4);
    MFMAQ(Aa, Bf1, 0);
    BARRIER();

    // ---- ph3: stage B r2,r3; bar; lgkm(0); MFMA (m1,k1) ----
    gll16(gBn + (long)128 * LD, lB + d + 2 * 4096);
    gll16(gBn + (long)192 * LD, lB + d + 3 * 4096);
    BARRIER();
    LGKM(0);
    MFMAQ(Abf, Bf1, 4);
    BARRIER();
  }

  // ---------------- epilogue (j-dim contiguous in output) ----------------
  const int rsub = (lane >> 4) * 4;

  if constexpr (MODE == 0) {
    // acc row = out-d, col = token. which = bm>>10 uniform per block.
    const int which = bm >> 10;
    const float* bp = which == 0 ? bias0 : (which == 1 ? bias1 : bias2);
    u16* Cq = (u16*)C0;
    u16* Ck = (u16*)C1;
    u16* Cv = (u16*)C2;
    const int od_base = (bm & 1023) + wr * 128 + rsub;
#pragma unroll
    for (int n = 0; n < 4; ++n) {
      int token = bn + wc * 64 + n * 16 + alane;
      u16* dst;
      if (which == 1) {
        int b = token >> 11, ss = token & 2047;
        dst = Ck + ((long)b * SKV + SCC + ss) * DM;
      } else if (which == 0) {
        dst = Cq + (long)token * DM;
      } else {
        dst = Cv + (long)token * DM;
      }
#pragma unroll
      for (int m = 0; m < 8; ++m) {
        int cc = od_base + m * 16;
        float4 bb = *(const float4*)(bp + cc);
        ushort4 u;
        u.x = f2bf(acc[m][n][0] + bb.x);
        u.y = f2bf(acc[m][n][1] + bb.y);
        u.z = f2bf(acc[m][n][2] + bb.z);
        u.w = f2bf(acc[m][n][3] + bb.w);
        *(ushort4*)(dst + cc) = u;
      }
    }
  } else if constexpr (MODE == 1) {
    // acc row = kv, col = q. store P[q][kv] ushort4; rowsum per q.
    u16* Pp = (u16*)C0 + (long)z * SQN * SKV;
    float* sb = sums + z * SQN;
    const float CE = 0.18033688011112042f;  // log2(e)/8
    const int kv_base = bm + wr * 128 + rsub;
#pragma unroll
    for (int n = 0; n < 4; ++n) {
      int q = bn + wc * 64 + n * 16 + alane;
      u16* prow = Pp + (long)q * SKV;
      float part = 0.f;
#pragma unroll
      for (int m = 0; m < 8; ++m) {
        int kv = kv_base + m * 16;
        float e0 = exp2f(acc[m][n][0] * CE);
        float e1 = exp2f(acc[m][n][1] * CE);
        float e2 = exp2f(acc[m][n][2] * CE);
        float e3 = exp2f(acc[m][n][3] * CE);
        part += (e0 + e1) + (e2 + e3);
        ushort4 u;
        u.x = f2bf(e0); u.y = f2bf(e1); u.z = f2bf(e2); u.w = f2bf(e3);
        *(ushort4*)(prow + kv) = u;
      }
      part += __shfl_xor(part, 16);
      part += __shfl_xor(part, 32);
      if ((lane >> 4) == 0) atomicAdd(&sb[q], part);
    }
  } else {
    // acc row = q, col = d. f32 stores, 64B segments per 16 lanes.
    float* Cp = (float*)C0 + (long)z * SQN * DM;
#pragma unroll
    for (int n = 0; n < 4; ++n) {
      int col = bn + wc * 64 + n * 16 + alane;
#pragma unroll
      for (int m = 0; m < 8; ++m)
#pragma unroll
        for (int j = 0; j < 4; ++j) {
          int row = bm + wr * 128 + m * 16 + rsub + j;
          Cp[(long)row * DM + col] = acc[m][n][j];
        }
    }
  }
}

// ---------------- reduce split-K partials + normalize ----------------
__global__ __launch_bounds__(256) void k_reduce(const float* __restrict__ Op,
                                                const float* __restrict__ sums,
                                                float* __restrict__ out) {
  const long n4 = (long)NB * SQN * DM / 4;
  long i = (long)blockIdx.x * 256 + threadIdx.x;
  if (i >= n4) return;
  long e = i * 4;
  int b = (int)(e / ((long)SQN * DM));
  long rem = e - (long)b * SQN * DM;
  int row = (int)(rem / DM);
  const long z4 = (long)SQN * DM / 4;
  long i0 = (long)(b * NSPLIT) * z4 + (rem >> 2);
  float4 a0 = ((const float4*)Op)[i0];
  float4 a1 = ((const float4*)Op)[i0 + z4];
  float inv = 1.0f / sums[b * SQN + row];
  float4 r;
  r.x = (a0.x + a1.x) * inv;
  r.y = (a0.y + a1.y) * inv;
  r.z = (a0.z + a1.z) * inv;
  r.w = (a0.w + a1.w) * inv;
  ((float4*)out)[i] = r;
}

// ---------------- launch ----------------
extern "C" void kernel_launch(void* const* d_in, const int* in_sizes, int n_in,
                              void* d_out, int out_size, void* d_ws, size_t ws_size,
                              hipStream_t stream) {
  const float* hidden = (const float*)d_in[0];
  const float* ck = (const float*)d_in[1];
  const float* cv = (const float*)d_in[2];
  const float* Wq = (const float*)d_in[3];
  const float* bq = (const float*)d_in[4];
  const float* Wk = (const float*)d_in[5];
  const float* bk = (const float*)d_in[6];
  const float* Wv = (const float*)d_in[7];
  const float* bv = (const float*)d_in[8];
  (void)in_sizes; (void)n_in; (void)out_size; (void)ws_size;

  hipFuncSetAttribute(reinterpret_cast<const void*>(&k_gemm8<0>),
                      hipFuncAttributeMaxDynamicSharedMemorySize, 131072);
  hipFuncSetAttribute(reinterpret_cast<const void*>(&k_gemm8<1>),
                      hipFuncAttributeMaxDynamicSharedMemorySize, 131072);
  hipFuncSetAttribute(reinterpret_cast<const void*>(&k_gemm8<2>),
                      hipFuncAttributeMaxDynamicSharedMemorySize, 131072);

  char* base = (char*)d_ws;
  size_t off = 0;
  auto alloc = [&](size_t bytes) {
    char* p = base + off;
    off = (off + bytes + 255) & ~(size_t)255;
    return p;
  };
  // region0 (dead before PV): Hb, weights, Qb, Kb, Vtmp. Opart aliases it.
  u16* Hb = (u16*)alloc((size_t)NB * SQN * DM * 2);
  u16* Wall = (u16*)alloc((size_t)3 * DM * DM * 2);  // Wq|Wk|Wv stacked
  u16* Qb = (u16*)alloc((size_t)NB * SQN * DM * 2);
  u16* Kb = (u16*)alloc((size_t)NB * SKV * DM * 2);
  u16* Vtmp = (u16*)alloc((size_t)NB * SQN * DM * 2);
  float* Opart = (float*)base;  // [NB*NSPLIT][2048][1024] f32, aliases region0
  size_t opart_bytes = (size_t)NB * NSPLIT * SQN * DM * 4;
  if (off < opart_bytes) off = (opart_bytes + 255) & ~(size_t)255;
  u16* VT = (u16*)alloc((size_t)NB * DM * SKV * 2);
  u16* P = (u16*)alloc((size_t)NB * SQN * SKV * 2);
  float* sums = (float*)alloc((size_t)NB * SQN * 4);

  // conversions
  k_cvt<<<2048, 256, 0, stream>>>(hidden, Hb, (long)NB * SQN * DM / 4);
  k_cvt<<<512, 256, 0, stream>>>(Wq, Wall, (long)DM * DM / 4);
  k_cvt<<<512, 256, 0, stream>>>(Wk, Wall + (size_t)DM * DM, (long)DM * DM / 4);
  k_cvt<<<512, 256, 0, stream>>>(Wv, Wall + (size_t)2 * DM * DM, (long)DM * DM / 4);
  k_cvt_ck<<<4096, 256, 0, stream>>>(ck, Kb);

  // fused QKV projection: A=W-stack [3072][1024], B=H [8192][1024]
  k_gemm8<0><<<dim3(32, 12, 1), 512, 131072, stream>>>(
      Wall, Hb, Qb, Kb, Vtmp, nullptr, bq, bk, bv);

  // V^T
  k_build_vt<<<dim3(SKV / 64, DM / 64, NB), 256, 0, stream>>>(cv, Vtmp, VT);

  // S^T = K.Q^T with fused exp + row sums (batched over 4): A=K, B=Q
  hipMemsetAsync(sums, 0, (size_t)NB * SQN * 4, stream);
  k_gemm8<1><<<dim3(SQN / 256, SKV / 256, NB), 512, 131072, stream>>>(
      Kb, Qb, P, nullptr, nullptr, sums, nullptr, nullptr, nullptr);

  // PV split-K(2): z = b*NSPLIT + split
  k_gemm8<2><<<dim3(DM / 256, SQN / 256, NB * NSPLIT), 512, 131072, stream>>>(
      P, VT, Opart, nullptr, nullptr, nullptr, nullptr, nullptr, nullptr);

  // reduce partials + normalize
  k_reduce<<<(NB * SQN * DM / 4 + 255) / 256, 256, 0, stream>>>(
      Opart, sums, (float*)d_out);
}